// Round 4
// baseline (1091.994 us; speedup 1.0000x reference)
//
#include <hip/hip_runtime.h>
#include <cstdint>
#include <cstddef>

#define E_ 8
#define T_ 1024
#define D_ 1024
#define I_ 5632
#define TWO_I_ 11264
#define NPAD_MAX 2176                 /* 2048 + 8*16 */
#define NGRP_MAX 136

// ws layout (bytes): int tables in [0,64K), then act_f, then xg_f, y overlays xg_f
#define WS_ACTF_B 65536
#define WS_XGF_B  (65536 + 24510464)              /* act_f = 136*180224      */
#define WS_Y_B    WS_XGF_B                        /* y overlays dead xg_f    */
// int-table offsets (units of 4 B)
#define WS_CNT   0
#define WS_BASEP 8
#define WS_ESLOT 16
#define WS_TOKW  2064
#define WS_ETOK  4112

typedef __attribute__((ext_vector_type(8))) __bf16 bf16x8;
typedef __attribute__((ext_vector_type(4))) float  f32x4;

__device__ __forceinline__ unsigned f2bf(float f) {
    unsigned u = __float_as_uint(f);
    u += 0x7fffu + ((u >> 16) & 1u);
    return u >> 16;
}
__device__ __forceinline__ unsigned pack2bf(float f0, float f1) {
    unsigned a0 = __float_as_uint(f0); a0 += 0x7fffu + ((a0 >> 16) & 1u);
    unsigned a1 = __float_as_uint(f1); a1 += 0x7fffu + ((a1 >> 16) & 1u);
    return (a0 >> 16) | (a1 & 0xffff0000u);
}

// ---------------------------------------------------------------- routing ---
__global__ void routing_kernel(const float* __restrict__ gate,
                               int* cnt, int* basep, int* eslot,
                               float* tokw, int* etok)
{
    int t = threadIdx.x;
    if (t < E_) cnt[t] = 0;
    __syncthreads();
    float g[E_];
#pragma unroll
    for (int e = 0; e < E_; ++e) g[e] = gate[t * E_ + e];
    int i0 = 0; float p0 = g[0];
#pragma unroll
    for (int e = 1; e < E_; ++e) if (g[e] > p0) { p0 = g[e]; i0 = e; }
    int i1 = -1; float p1 = -1e30f;
#pragma unroll
    for (int e = 0; e < E_; ++e) if (e != i0 && g[e] > p1) { p1 = g[e]; i1 = e; }
    float w0 = 1.0f / (1.0f + expf(p1 - p0));
    float w1 = 1.0f - w0;
    int s0 = atomicAdd(&cnt[i0], 1);
    int s1 = atomicAdd(&cnt[i1], 1);
    etok[i0 * T_ + s0] = t;
    etok[i1 * T_ + s1] = t;
    eslot[t * 2 + 0] = i0 * T_ + s0;  tokw[t * 2 + 0] = w0;
    eslot[t * 2 + 1] = i1 * T_ + s1;  tokw[t * 2 + 1] = w1;
    __syncthreads();
    if (t == 0) {
        int r = 0;
#pragma unroll
        for (int e = 0; e < E_; ++e) { basep[e] = r; r += (cnt[e] + 15) & ~15; }
    }
}

// ------------------- gather x rows, cast bf16, fragment-major swizzle -------
__global__ void gather_cast_kernel(const float* __restrict__ x,
                                   const int* __restrict__ cnt,
                                   const int* __restrict__ basep,
                                   const int* __restrict__ etok,
                                   unsigned short* __restrict__ xgf)
{
    int e = blockIdx.x >> 6, g = blockIdx.x & 63;
    int n = cnt[e];
    if (g * 16 >= n) return;
    int tid = threadIdx.x;
    int row = g * 16 + (tid & 15);
    row = min(row, n - 1);
    int tok = etok[e * T_ + row];
    const float* xr = x + (size_t)tok * D_;
    unsigned short* dst = xgf + ((size_t)(basep[e] >> 4) + g) * 16384;
#pragma unroll
    for (int it = 0; it < 8; ++it) {
        int c = it * 16 + (tid >> 4);          // k-chunk 0..127
        float4 v0 = *(const float4*)(xr + c * 8);
        float4 v1 = *(const float4*)(xr + c * 8 + 4);
        uint4 h;
        h.x = pack2bf(v0.x, v0.y); h.y = pack2bf(v0.z, v0.w);
        h.z = pack2bf(v1.x, v1.y); h.w = pack2bf(v1.z, v1.w);
        *(uint4*)(dst + c * 128 + (tid & 15) * 8) = h;
    }
}

// ------------------------------------------------- gemm1: xg@w1 + silu -----
// grid = E_*44, block 1024 thr = 16 waves (4 mh x 4 colg), wave 64x64.
// Block tile 256 rows x 256 cols (128 gate + 128 up). B loads: dwordx4 over
// 4 consecutive cols -> 512-B contiguous runs per wave-instruction (the HBM
// granule fix). Producer-side dequant into swizzled per-column LDS chunks
// ([col][k/8][k%8], XOR ((col>>2)&3)<<4 on the k-chunk bits -> conflict-free
// b128 fragment reads). One raw s_barrier + lgkmcnt(0) per BK=32 stage,
// vmcnt never drained, 2-deep B prefetch.
__global__ __launch_bounds__(1024) void gemm1_kernel(
    const unsigned short* __restrict__ xgf, const int* __restrict__ w1q,
    const float* __restrict__ w1s, const int* __restrict__ cnt,
    const int* __restrict__ basep, unsigned short* __restrict__ actf)
{
    __shared__ unsigned char blds[2][16384];
    int cg = blockIdx.x % 44, e = blockIdx.x / 44;
    int n = cnt[e];
    if (n <= 0) return;
    int npad = (n + 15) & ~15;
    int pb = basep[e];
    int tid = threadIdx.x, lane = tid & 63, w = tid >> 6;
    int l15 = lane & 15, lq = lane >> 4;
    int colg = w & 3, mh = w >> 2;

    // staging role: thread -> 4 consecutive cols (colq*4) x k-rows {kg, kg+16}
    int colq = lane, kg = w;
    int col0 = colq * 4;
    int jb = (col0 < 128) ? (cg * 128 + col0) : (I_ + cg * 128 + (col0 - 128));
    const int*   gq  = w1q + ((size_t)e * 1024 + kg) * TWO_I_ + jb;
    const float* sqp = w1s + (size_t)e * 8 * TWO_I_ + jb;
    unsigned wb  = (unsigned)colq * 256 + (unsigned)(kg & 7) * 2;
    unsigned ch0 = (unsigned)((((kg >> 3)    ) ^ (colq & 3)) << 4);
    unsigned ch1 = (unsigned)((((kg >> 3) + 2) ^ (colq & 3)) << 4);
    unsigned srdb = (unsigned)(colg * 16 + l15) * 64
                  + (unsigned)(((lq ^ (l15 >> 2)) & 3) * 16);

    int4  PA0, PA1, PB0, PB1;
    float4 SA, SB;

#define G1_ISSUE(S, P0, P1, SS)                                             \
    { P0 = *(const int4*)(gq + (size_t)(S) * 32 * TWO_I_);                  \
      P1 = *(const int4*)(gq + ((size_t)(S) * 32 + 16) * TWO_I_);           \
      SS = *(const float4*)(sqp + (size_t)((S) >> 2) * TWO_I_); }

#define G1_DEQW(S, P0, P1, SS)                                              \
    { unsigned char* bp = &blds[(S) & 1][0];                                \
      *(unsigned short*)(bp + wb +   0 + ch0) = (unsigned short)f2bf((float)P0.x * SS.x - 8.f * SS.x); \
      *(unsigned short*)(bp + wb +  64 + ch0) = (unsigned short)f2bf((float)P0.y * SS.y - 8.f * SS.y); \
      *(unsigned short*)(bp + wb + 128 + ch0) = (unsigned short)f2bf((float)P0.z * SS.z - 8.f * SS.z); \
      *(unsigned short*)(bp + wb + 192 + ch0) = (unsigned short)f2bf((float)P0.w * SS.w - 8.f * SS.w); \
      *(unsigned short*)(bp + wb +   0 + ch1) = (unsigned short)f2bf((float)P1.x * SS.x - 8.f * SS.x); \
      *(unsigned short*)(bp + wb +  64 + ch1) = (unsigned short)f2bf((float)P1.y * SS.y - 8.f * SS.y); \
      *(unsigned short*)(bp + wb + 128 + ch1) = (unsigned short)f2bf((float)P1.z * SS.z - 8.f * SS.z); \
      *(unsigned short*)(bp + wb + 192 + ch1) = (unsigned short)f2bf((float)P1.w * SS.w - 8.f * SS.w); }

    for (int tb = 0; tb < npad; tb += 256) {
        int aoff[4];
#pragma unroll
        for (int mi = 0; mi < 4; ++mi) {
            int R = tb + mh * 64 + mi * 16;
            R = min(R, npad - 16);
            aoff[mi] = ((pb + R) >> 4) * 32768;
        }
        const char* abase = (const char*)xgf + lq * 256 + l15 * 16;

        f32x4 acc[4][4];
#pragma unroll
        for (int mi = 0; mi < 4; ++mi)
#pragma unroll
            for (int nf = 0; nf < 4; ++nf)
                acc[mi][nf] = (f32x4){0.f, 0.f, 0.f, 0.f};

        G1_ISSUE(0, PA0, PA1, SA);
        G1_ISSUE(1, PB0, PB1, SB);
        G1_DEQW(0, PA0, PA1, SA);
        G1_ISSUE(2, PA0, PA1, SA);
        asm volatile("s_waitcnt lgkmcnt(0)" ::: "memory");
        __builtin_amdgcn_s_barrier();
        asm volatile("" ::: "memory");

#pragma unroll 2
        for (int s = 0; s < 32; ++s) {
            const char* at = abase + (size_t)s * 1024;
            bf16x8 a[4];
#pragma unroll
            for (int mi = 0; mi < 4; ++mi)
                a[mi] = *(const bf16x8*)(at + aoff[mi]);
            if (s + 1 < 32) {
                if ((s + 1) & 1) { G1_DEQW(s + 1, PB0, PB1, SB); }
                else             { G1_DEQW(s + 1, PA0, PA1, SA); }
            }
            if (s + 3 < 32) {
                if ((s + 3) & 1) { G1_ISSUE(s + 3, PB0, PB1, SB); }
                else             { G1_ISSUE(s + 3, PA0, PA1, SA); }
            }
            const unsigned char* bp = &blds[s & 1][0];
            bf16x8 b0 = *(const bf16x8*)(bp + srdb);
            bf16x8 b1 = *(const bf16x8*)(bp + srdb + 4096);
            bf16x8 b2 = *(const bf16x8*)(bp + srdb + 8192);
            bf16x8 b3 = *(const bf16x8*)(bp + srdb + 12288);
            __builtin_amdgcn_s_setprio(1);
#pragma unroll
            for (int mi = 0; mi < 4; ++mi) {
                acc[mi][0] = __builtin_amdgcn_mfma_f32_16x16x32_bf16(a[mi], b0, acc[mi][0], 0, 0, 0);
                acc[mi][1] = __builtin_amdgcn_mfma_f32_16x16x32_bf16(a[mi], b1, acc[mi][1], 0, 0, 0);
                acc[mi][2] = __builtin_amdgcn_mfma_f32_16x16x32_bf16(a[mi], b2, acc[mi][2], 0, 0, 0);
                acc[mi][3] = __builtin_amdgcn_mfma_f32_16x16x32_bf16(a[mi], b3, acc[mi][3], 0, 0, 0);
            }
            __builtin_amdgcn_s_setprio(0);
            asm volatile("s_waitcnt lgkmcnt(0)" ::: "memory");
            __builtin_amdgcn_s_barrier();
            asm volatile("" ::: "memory");
        }
        // epilogue: silu(gate)*up -> act_f fragment-major
#pragma unroll
        for (int mi = 0; mi < 4; ++mi) {
#pragma unroll
            for (int r = 0; r < 4; ++r) {
                int m = tb + mh * 64 + mi * 16 + lq * 4 + r;
                if (m < npad) {
                    int prow = pb + m;
                    size_t rg = (size_t)(prow >> 4) * 90112 + (prow & 15) * 8;
                    {
                        float gv = acc[mi][0][r], uv = acc[mi][2][r];
                        float av = gv / (1.f + __expf(-gv)) * uv;
                        int icol = cg * 128 + colg * 16 + l15;
                        actf[rg + (icol >> 3) * 128 + (icol & 7)] = (unsigned short)f2bf(av);
                    }
                    {
                        float gv = acc[mi][1][r], uv = acc[mi][3][r];
                        float av = gv / (1.f + __expf(-gv)) * uv;
                        int icol = cg * 128 + 64 + colg * 16 + l15;
                        actf[rg + (icol >> 3) * 128 + (icol & 7)] = (unsigned short)f2bf(av);
                    }
                }
            }
        }
    }
#undef G1_ISSUE
#undef G1_DEQW
}

// ---------------------------------------------------- gemm2: act@w2 --------
// grid = E_*4dt*8seg = 256 blocks x 1024 thr. Block 256 rows x 256 cols,
// K/seg = 704 (22 stages). B loads: dwordx4 -> full 1-KB contiguous runs.
__global__ __launch_bounds__(1024) void gemm2_kernel(
    const unsigned short* __restrict__ actf, const int* __restrict__ w2q,
    const float* __restrict__ w2s, const int* __restrict__ cnt,
    const int* __restrict__ basep, float* __restrict__ y)
{
    __shared__ unsigned char blds[2][16384];
    int bid = blockIdx.x;
    int seg = bid & 7, dt = (bid >> 3) & 3, e = bid >> 5;
    int n = cnt[e];
    if (n <= 0) return;
    int npad = (n + 15) & ~15;
    int pb = basep[e];
    int tid = threadIdx.x, lane = tid & 63, w = tid >> 6;
    int l15 = lane & 15, lq = lane >> 4;
    int colg = w & 3, mh = w >> 2;
    int kbase = seg * 704;

    int colq = lane, kg = w;
    const int*   gq  = w2q + ((size_t)e * 5632 + kbase + kg) * 1024 + dt * 256 + colq * 4;
    const float* sqp = w2s + (size_t)e * 44 * 1024 + dt * 256 + colq * 4;
    unsigned wb  = (unsigned)colq * 256 + (unsigned)(kg & 7) * 2;
    unsigned ch0 = (unsigned)((((kg >> 3)    ) ^ (colq & 3)) << 4);
    unsigned ch1 = (unsigned)((((kg >> 3) + 2) ^ (colq & 3)) << 4);
    unsigned srdb = (unsigned)(colg * 16 + l15) * 64
                  + (unsigned)(((lq ^ (l15 >> 2)) & 3) * 16);

    int4  PA0, PA1, PB0, PB1;
    float4 SA, SB;

#define G2_ISSUE(S, P0, P1, SS)                                             \
    { P0 = *(const int4*)(gq + (size_t)(S) * 32 * 1024);                    \
      P1 = *(const int4*)(gq + ((size_t)(S) * 32 + 16) * 1024);             \
      SS = *(const float4*)(sqp + (size_t)((kbase + (S) * 32) >> 7) * 1024); }

#define G2_DEQW(S, P0, P1, SS)                                              \
    { unsigned char* bp = &blds[(S) & 1][0];                                \
      *(unsigned short*)(bp + wb +   0 + ch0) = (unsigned short)f2bf((float)P0.x * SS.x - 8.f * SS.x); \
      *(unsigned short*)(bp + wb +  64 + ch0) = (unsigned short)f2bf((float)P0.y * SS.y - 8.f * SS.y); \
      *(unsigned short*)(bp + wb + 128 + ch0) = (unsigned short)f2bf((float)P0.z * SS.z - 8.f * SS.z); \
      *(unsigned short*)(bp + wb + 192 + ch0) = (unsigned short)f2bf((float)P0.w * SS.w - 8.f * SS.w); \
      *(unsigned short*)(bp + wb +   0 + ch1) = (unsigned short)f2bf((float)P1.x * SS.x - 8.f * SS.x); \
      *(unsigned short*)(bp + wb +  64 + ch1) = (unsigned short)f2bf((float)P1.y * SS.y - 8.f * SS.y); \
      *(unsigned short*)(bp + wb + 128 + ch1) = (unsigned short)f2bf((float)P1.z * SS.z - 8.f * SS.z); \
      *(unsigned short*)(bp + wb + 192 + ch1) = (unsigned short)f2bf((float)P1.w * SS.w - 8.f * SS.w); }

    for (int tb = 0; tb < npad; tb += 256) {
        int aoff[4];
#pragma unroll
        for (int mi = 0; mi < 4; ++mi) {
            int R = tb + mh * 64 + mi * 16;
            R = min(R, npad - 16);
            aoff[mi] = ((pb + R) >> 4) * 180224;
        }
        const char* abase = (const char*)actf + seg * 22528 + lq * 256 + l15 * 16;

        f32x4 acc[4][4];
#pragma unroll
        for (int mi = 0; mi < 4; ++mi)
#pragma unroll
            for (int nf = 0; nf < 4; ++nf)
                acc[mi][nf] = (f32x4){0.f, 0.f, 0.f, 0.f};

        G2_ISSUE(0, PA0, PA1, SA);
        G2_ISSUE(1, PB0, PB1, SB);
        G2_DEQW(0, PA0, PA1, SA);
        G2_ISSUE(2, PA0, PA1, SA);
        asm volatile("s_waitcnt lgkmcnt(0)" ::: "memory");
        __builtin_amdgcn_s_barrier();
        asm volatile("" ::: "memory");

#pragma unroll 2
        for (int s = 0; s < 22; ++s) {
            const char* at = abase + (size_t)s * 1024;
            bf16x8 a[4];
#pragma unroll
            for (int mi = 0; mi < 4; ++mi)
                a[mi] = *(const bf16x8*)(at + aoff[mi]);
            if (s + 1 < 22) {
                if ((s + 1) & 1) { G2_DEQW(s + 1, PB0, PB1, SB); }
                else             { G2_DEQW(s + 1, PA0, PA1, SA); }
            }
            if (s + 3 < 22) {
                if ((s + 3) & 1) { G2_ISSUE(s + 3, PB0, PB1, SB); }
                else             { G2_ISSUE(s + 3, PA0, PA1, SA); }
            }
            const unsigned char* bp = &blds[s & 1][0];
            bf16x8 b0 = *(const bf16x8*)(bp + srdb);
            bf16x8 b1 = *(const bf16x8*)(bp + srdb + 4096);
            bf16x8 b2 = *(const bf16x8*)(bp + srdb + 8192);
            bf16x8 b3 = *(const bf16x8*)(bp + srdb + 12288);
            __builtin_amdgcn_s_setprio(1);
#pragma unroll
            for (int mi = 0; mi < 4; ++mi) {
                acc[mi][0] = __builtin_amdgcn_mfma_f32_16x16x32_bf16(a[mi], b0, acc[mi][0], 0, 0, 0);
                acc[mi][1] = __builtin_amdgcn_mfma_f32_16x16x32_bf16(a[mi], b1, acc[mi][1], 0, 0, 0);
                acc[mi][2] = __builtin_amdgcn_mfma_f32_16x16x32_bf16(a[mi], b2, acc[mi][2], 0, 0, 0);
                acc[mi][3] = __builtin_amdgcn_mfma_f32_16x16x32_bf16(a[mi], b3, acc[mi][3], 0, 0, 0);
            }
            __builtin_amdgcn_s_setprio(0);
            asm volatile("s_waitcnt lgkmcnt(0)" ::: "memory");
            __builtin_amdgcn_s_barrier();
            asm volatile("" ::: "memory");
        }
#pragma unroll
        for (int mi = 0; mi < 4; ++mi) {
#pragma unroll
            for (int r = 0; r < 4; ++r) {
                int m = tb + mh * 64 + mi * 16 + lq * 4 + r;
                if (m < n) {
                    float* yr = y + ((size_t)seg * NPAD_MAX + pb + m) * 1024;
                    int dc = dt * 256 + colg * 16 + l15;
                    yr[dc]       = acc[mi][0][r];
                    yr[dc + 64]  = acc[mi][1][r];
                    yr[dc + 128] = acc[mi][2][r];
                    yr[dc + 192] = acc[mi][3][r];
                }
            }
        }
    }
#undef G2_ISSUE
#undef G2_DEQW
}

// --------------------------------------------------------------- combine ---
__global__ void combine_kernel(const float* __restrict__ y,
                               const int* __restrict__ eslot,
                               const float* __restrict__ tokw,
                               const int* __restrict__ basep,
                               float* __restrict__ out)
{
    int idx = blockIdx.x * blockDim.x + threadIdx.x;
    int t  = idx >> 8;
    int dc = idx & 255;
    int es0 = eslot[t * 2 + 0], es1 = eslot[t * 2 + 1];
    float w0 = tokw[t * 2 + 0], w1 = tokw[t * 2 + 1];
    int p0 = basep[es0 >> 10] + (es0 & 1023);
    int p1 = basep[es1 >> 10] + (es1 & 1023);
    const float4* y4 = (const float4*)y;
    float4 o = (float4){0.f, 0.f, 0.f, 0.f};
#pragma unroll
    for (int seg = 0; seg < 8; ++seg) {
        float4 a = y4[((size_t)seg * NPAD_MAX + p0) * 256 + dc];
        float4 b = y4[((size_t)seg * NPAD_MAX + p1) * 256 + dc];
        o.x += w0 * a.x + w1 * b.x;
        o.y += w0 * a.y + w1 * b.y;
        o.z += w0 * a.z + w1 * b.z;
        o.w += w0 * a.w + w1 * b.w;
    }
    ((float4*)out)[idx] = o;
}

// ---------------------------------------------------------------- launch ---
extern "C" void kernel_launch(void* const* d_in, const int* in_sizes, int n_in,
                              void* d_out, int out_size, void* d_ws, size_t ws_size,
                              hipStream_t stream)
{
    const float* x    = (const float*)d_in[0];
    const float* gate = (const float*)d_in[1];
    const int*   w1q  = (const int*)d_in[2];
    const int*   w2q  = (const int*)d_in[3];
    const float* w1s  = (const float*)d_in[4];
    const float* w2s  = (const float*)d_in[5];
    float* out = (float*)d_out;
    int*   wsi = (int*)d_ws;
    float* wsf = (float*)d_ws;

    int*   cnt   = wsi + WS_CNT;
    int*   basep = wsi + WS_BASEP;
    int*   eslot = wsi + WS_ESLOT;
    float* tokw  = wsf + WS_TOKW;
    int*   etok  = wsi + WS_ETOK;
    unsigned short* actf = (unsigned short*)((char*)d_ws + WS_ACTF_B);
    unsigned short* xgf  = (unsigned short*)((char*)d_ws + WS_XGF_B);
    float*          y    = (float*)((char*)d_ws + WS_Y_B);

    routing_kernel<<<1, 1024, 0, stream>>>(gate, cnt, basep, eslot, tokw, etok);
    gather_cast_kernel<<<E_ * 64, 256, 0, stream>>>(x, cnt, basep, etok, xgf);
    gemm1_kernel<<<E_ * 44, 1024, 0, stream>>>(xgf, w1q, w1s, cnt, basep, actf);
    gemm2_kernel<<<E_ * 4 * 8, 1024, 0, stream>>>(actf, w2q, w2s, cnt, basep, y);
    combine_kernel<<<(T_ * D_ / 4) / 256, 256, 0, stream>>>(y, eslot, tokw, basep, out);
}

// Round 5
// 866.378 us; speedup vs baseline: 1.2604x; 1.2604x over previous
//
#include <hip/hip_runtime.h>
#include <cstdint>
#include <cstddef>

#define E_ 8
#define T_ 1024
#define D_ 1024
#define I_ 5632
#define TWO_I_ 11264
#define NPAD_MAX 2176                 /* 2048 + 8*16 */
#define NGRP_MAX 136

// ws layout (bytes): int tables in [0,64K), then act_f, then xg_f, y overlays xg_f
#define WS_ACTF_B 65536
#define WS_XGF_B  (65536 + 24510464)              /* act_f = 136*180224      */
#define WS_Y_B    WS_XGF_B                        /* y overlays dead xg_f    */
// int-table offsets (units of 4 B)
#define WS_CNT   0
#define WS_BASEP 8
#define WS_ESLOT 16
#define WS_TOKW  2064
#define WS_ETOK  4112

typedef __attribute__((ext_vector_type(8))) __bf16 bf16x8;
typedef __attribute__((ext_vector_type(4))) float  f32x4;

__device__ __forceinline__ unsigned f2bf(float f) {
    unsigned u = __float_as_uint(f);
    u += 0x7fffu + ((u >> 16) & 1u);
    return u >> 16;
}
__device__ __forceinline__ unsigned pack2bf(float f0, float f1) {
    unsigned a0 = __float_as_uint(f0); a0 += 0x7fffu + ((a0 >> 16) & 1u);
    unsigned a1 = __float_as_uint(f1); a1 += 0x7fffu + ((a1 >> 16) & 1u);
    return (a0 >> 16) | (a1 & 0xffff0000u);
}
#define QC(P, c) ((c) == 0 ? (P).x : (c) == 1 ? (P).y : (c) == 2 ? (P).z : (P).w)

// ---------------------------------------------------------------- routing ---
__global__ void routing_kernel(const float* __restrict__ gate,
                               int* cnt, int* basep, int* eslot,
                               float* tokw, int* etok)
{
    int t = threadIdx.x;
    if (t < E_) cnt[t] = 0;
    __syncthreads();
    float g[E_];
#pragma unroll
    for (int e = 0; e < E_; ++e) g[e] = gate[t * E_ + e];
    int i0 = 0; float p0 = g[0];
#pragma unroll
    for (int e = 1; e < E_; ++e) if (g[e] > p0) { p0 = g[e]; i0 = e; }
    int i1 = -1; float p1 = -1e30f;
#pragma unroll
    for (int e = 0; e < E_; ++e) if (e != i0 && g[e] > p1) { p1 = g[e]; i1 = e; }
    float w0 = 1.0f / (1.0f + expf(p1 - p0));
    float w1 = 1.0f - w0;
    int s0 = atomicAdd(&cnt[i0], 1);
    int s1 = atomicAdd(&cnt[i1], 1);
    etok[i0 * T_ + s0] = t;
    etok[i1 * T_ + s1] = t;
    eslot[t * 2 + 0] = i0 * T_ + s0;  tokw[t * 2 + 0] = w0;
    eslot[t * 2 + 1] = i1 * T_ + s1;  tokw[t * 2 + 1] = w1;
    __syncthreads();
    if (t == 0) {
        int r = 0;
#pragma unroll
        for (int e = 0; e < E_; ++e) { basep[e] = r; r += (cnt[e] + 15) & ~15; }
    }
}

// ------------------- gather x rows, cast bf16, fragment-major swizzle -------
__global__ void gather_cast_kernel(const float* __restrict__ x,
                                   const int* __restrict__ cnt,
                                   const int* __restrict__ basep,
                                   const int* __restrict__ etok,
                                   unsigned short* __restrict__ xgf)
{
    int e = blockIdx.x >> 6, g = blockIdx.x & 63;
    int n = cnt[e];
    if (g * 16 >= n) return;
    int tid = threadIdx.x;
    int row = g * 16 + (tid & 15);
    row = min(row, n - 1);
    int tok = etok[e * T_ + row];
    const float* xr = x + (size_t)tok * D_;
    unsigned short* dst = xgf + ((size_t)(basep[e] >> 4) + g) * 16384;
#pragma unroll
    for (int it = 0; it < 8; ++it) {
        int c = it * 16 + (tid >> 4);          // k-chunk 0..127
        float4 v0 = *(const float4*)(xr + c * 8);
        float4 v1 = *(const float4*)(xr + c * 8 + 4);
        uint4 h;
        h.x = pack2bf(v0.x, v0.y); h.y = pack2bf(v0.z, v0.w);
        h.z = pack2bf(v1.x, v1.y); h.w = pack2bf(v1.z, v1.w);
        *(uint4*)(dst + c * 128 + (tid & 15) * 8) = h;
    }
}

// ------------------------------------------------- gemm1: xg@w1 + silu -----
// grid = E_*44, 512 thr (8 waves: 2 mh x 4 colg). Tile: M=128 x 128 out-cols
// (= 256 B-cols: 128 gate + 128 up). BK=64, 16 stages. Staging: thread owns
// 4 cols x 8 k (8x dwordx4 = 512-B contiguous runs), in-register dequant,
// 4x ds_write_b128 full cells into XOR-swizzled cell slots (conflict-free,
// verified bijective). Raw barrier + lgkmcnt(0); vmcnt never drained; A-loads
// pinned before B-issue (sched_barrier) so counted waits keep B in flight.
__global__ __launch_bounds__(512, 2) void gemm1_kernel(
    const unsigned short* __restrict__ xgf, const int* __restrict__ w1q,
    const float* __restrict__ w1s, const int* __restrict__ cnt,
    const int* __restrict__ basep, unsigned short* __restrict__ actf)
{
    __shared__ unsigned char blds[2][32768];
    int cg = blockIdx.x % 44, e = blockIdx.x / 44;
    int n = cnt[e];
    if (n <= 0) return;
    int npad = (n + 15) & ~15;
    int pb = basep[e];
    int tid = threadIdx.x, lane = tid & 63, w = tid >> 6;
    int l15 = lane & 15, lq = lane >> 4;
    int colg = w & 3, mh = w >> 2;

    // ---- staging role: thread (colq 0..63, kc 0..7) owns 4 cols x 8 k ----
    int colq = lane, kc = w;
    int col0 = colq * 4;
    int jb = (col0 < 128) ? (cg * 128 + col0) : (I_ + cg * 128 + (col0 - 128));
    const int*   gq  = w1q + (size_t)e * 1024 * TWO_I_ + jb;
    const float* sqp = w1s + (size_t)e * 8 * TWO_I_ + jb;
    int fcw  = colq >> 2;                       // 0..15
    int pzw  = (fcw & 3) | ((fcw >> 2) << 4);
    int lanp = (kc & 3) * 16 + (colq & 3) * 4;
    unsigned wro[4];
#pragma unroll
    for (int c = 0; c < 4; ++c)
        wro[c] = (unsigned)(fcw * 2048 + (kc >> 2) * 1024 + (((lanp + c) ^ pzw) << 4));

    // ---- compute-side B-fragment read offsets (XOR matches write) ----
    unsigned rdo[4];
#pragma unroll
    for (int nf = 0; nf < 4; ++nf) {
        int fc = (nf < 2) ? (2 * colg + nf) : (8 + 2 * colg + (nf - 2));
        int pz = (fc & 3) | ((fc >> 2) << 4);
        rdo[nf] = (unsigned)(fc * 2048 + ((lane ^ pz) << 4));
    }

    int4  Pa[8], Pb[8];
    float4 Sa, Sb;

#define G1_ISSUE(S, P, SS)                                                  \
    { const int* gp_ = gq + (size_t)((S) * 64 + kc * 8) * TWO_I_;           \
      _Pragma("unroll")                                                     \
      for (int j_ = 0; j_ < 8; ++j_)                                        \
          P[j_] = *(const int4*)(gp_ + (size_t)j_ * TWO_I_);                \
      SS = *(const float4*)(sqp + (size_t)((S) >> 1) * TWO_I_); }

#define G1_DEQW(S, P, SS)                                                   \
    { unsigned char* bp_ = &blds[(S) & 1][0];                               \
      _Pragma("unroll")                                                     \
      for (int c_ = 0; c_ < 4; ++c_) {                                      \
          float s_ = QC(SS, c_);                                            \
          float o_ = -8.f * s_;                                             \
          uint4 h_;                                                         \
          h_.x = pack2bf((float)QC(P[0], c_) * s_ + o_, (float)QC(P[1], c_) * s_ + o_); \
          h_.y = pack2bf((float)QC(P[2], c_) * s_ + o_, (float)QC(P[3], c_) * s_ + o_); \
          h_.z = pack2bf((float)QC(P[4], c_) * s_ + o_, (float)QC(P[5], c_) * s_ + o_); \
          h_.w = pack2bf((float)QC(P[6], c_) * s_ + o_, (float)QC(P[7], c_) * s_ + o_); \
          *(uint4*)(bp_ + wro[c_]) = h_;                                    \
      } }

#define G1_STAGE(S, PD, SD, PI, SI)                                         \
    { const char* at_ = abase + (size_t)(S) * 2048;                         \
      bf16x8 a0_[4], a1_[4];                                                \
      _Pragma("unroll")                                                     \
      for (int mi_ = 0; mi_ < 4; ++mi_) a0_[mi_] = *(const bf16x8*)(at_ + aoff[mi_]); \
      _Pragma("unroll")                                                     \
      for (int mi_ = 0; mi_ < 4; ++mi_) a1_[mi_] = *(const bf16x8*)(at_ + 1024 + aoff[mi_]); \
      __builtin_amdgcn_sched_barrier(0);                                    \
      if ((S) + 2 < 16) { G1_ISSUE((S) + 2, PI, SI) }                       \
      __builtin_amdgcn_sched_barrier(0);                                    \
      const unsigned char* bp_ = &blds[(S) & 1][0];                         \
      __builtin_amdgcn_s_setprio(1);                                        \
      _Pragma("unroll")                                                     \
      for (int nf_ = 0; nf_ < 4; ++nf_) {                                   \
          bf16x8 b0_ = *(const bf16x8*)(bp_ + rdo[nf_]);                    \
          bf16x8 b1_ = *(const bf16x8*)(bp_ + rdo[nf_] + 1024);             \
          _Pragma("unroll")                                                 \
          for (int mi_ = 0; mi_ < 4; ++mi_) {                               \
              acc[mi_][nf_] = __builtin_amdgcn_mfma_f32_16x16x32_bf16(a0_[mi_], b0_, acc[mi_][nf_], 0, 0, 0); \
              acc[mi_][nf_] = __builtin_amdgcn_mfma_f32_16x16x32_bf16(a1_[mi_], b1_, acc[mi_][nf_], 0, 0, 0); \
          } }                                                               \
      __builtin_amdgcn_s_setprio(0);                                        \
      if ((S) + 1 < 16) { G1_DEQW((S) + 1, PD, SD) }                        \
      asm volatile("s_waitcnt lgkmcnt(0)" ::: "memory");                    \
      __builtin_amdgcn_s_barrier();                                         \
      asm volatile("" ::: "memory"); }

    const char* abase = (const char*)xgf + lq * 256 + l15 * 16;

    for (int tb = 0; tb < npad; tb += 128) {
        int aoff[4];
#pragma unroll
        for (int mi = 0; mi < 4; ++mi) {
            int R = tb + mh * 64 + mi * 16;
            R = min(R, npad - 16);
            aoff[mi] = ((pb + R) >> 4) * 32768;
        }
        f32x4 acc[4][4];
#pragma unroll
        for (int mi = 0; mi < 4; ++mi)
#pragma unroll
            for (int nf = 0; nf < 4; ++nf)
                acc[mi][nf] = (f32x4){0.f, 0.f, 0.f, 0.f};

        G1_ISSUE(0, Pa, Sa)
        G1_ISSUE(1, Pb, Sb)
        G1_DEQW(0, Pa, Sa)
        asm volatile("s_waitcnt lgkmcnt(0)" ::: "memory");
        __builtin_amdgcn_s_barrier();
        asm volatile("" ::: "memory");

#pragma unroll 1
        for (int s2 = 0; s2 < 8; ++s2) {
            G1_STAGE(2 * s2,     Pb, Sb, Pa, Sa)
            G1_STAGE(2 * s2 + 1, Pa, Sa, Pb, Sb)
        }

        // epilogue: silu(gate)*up -> act_f fragment-major
#pragma unroll
        for (int mi = 0; mi < 4; ++mi) {
#pragma unroll
            for (int r = 0; r < 4; ++r) {
                int m = tb + mh * 64 + mi * 16 + lq * 4 + r;
                if (m < npad) {
                    int prow = pb + m;
                    size_t rg = (size_t)(prow >> 4) * 90112 + (prow & 15) * 8;
#pragma unroll
                    for (int nf = 0; nf < 2; ++nf) {
                        float gv = acc[mi][nf][r], uv = acc[mi][nf + 2][r];
                        float av = gv / (1.f + __expf(-gv)) * uv;
                        int icol = cg * 128 + (2 * colg + nf) * 16 + l15;
                        actf[rg + (icol >> 3) * 128 + (icol & 7)] = (unsigned short)f2bf(av);
                    }
                }
            }
        }
    }
#undef G1_ISSUE
#undef G1_DEQW
#undef G1_STAGE
}

// ---------------------------------------------------- gemm2: act@w2 --------
// grid = E_*8dt*4seg = 256 blocks, 512 thr. Tile M=128 x 128 cols, BK=128,
// K/seg = 1408 (11 stages). Staging: thread (colq 0..31, kc 0..15) owns
// 4 cols x 8 k; per dwordx4 instr: 2 x 512-B runs. Same XOR cell swizzle
// (P = (fc&3)|((fc>>2)<<5), fc 0..7).
__global__ __launch_bounds__(512, 2) void gemm2_kernel(
    const unsigned short* __restrict__ actf, const int* __restrict__ w2q,
    const float* __restrict__ w2s, const int* __restrict__ cnt,
    const int* __restrict__ basep, float* __restrict__ y)
{
    __shared__ unsigned char blds[2][32768];
    int bid = blockIdx.x;
    int seg = bid & 3, dt = (bid >> 2) & 7, e = bid >> 5;
    int n = cnt[e];
    if (n <= 0) return;
    int npad = (n + 15) & ~15;
    int pb = basep[e];
    int tid = threadIdx.x, lane = tid & 63, w = tid >> 6;
    int l15 = lane & 15, lq = lane >> 4;
    int colg = w & 3, mh = w >> 2;

    int colq = tid & 31, kc = tid >> 5;        // colq 0..31, kc 0..15
    const int*   gq  = w2q + ((size_t)e * 5632 + seg * 1408) * 1024 + dt * 128 + colq * 4;
    const float* sqp = w2s + ((size_t)e * 44 + seg * 11) * 1024 + dt * 128 + colq * 4;
    int fcw  = colq >> 2;                      // 0..7
    int pzw  = (fcw & 3) | ((fcw >> 2) << 5);
    int lanp = (kc & 3) * 16 + (colq & 3) * 4;
    unsigned wro[4];
#pragma unroll
    for (int c = 0; c < 4; ++c)
        wro[c] = (unsigned)(fcw * 4096 + (kc >> 2) * 1024 + (((lanp + c) ^ pzw) << 4));

    unsigned rdo[2];
#pragma unroll
    for (int nf = 0; nf < 2; ++nf) {
        int fc = 2 * colg + nf;
        int pz = (fc & 3) | ((fc >> 2) << 5);
        rdo[nf] = (unsigned)(fc * 4096 + ((lane ^ pz) << 4));
    }

    int4  Pa[8], Pb[8];
    float4 Sa, Sb;

#define G2_ISSUE(S, P, SS)                                                  \
    { const int* gp_ = gq + (size_t)((S) * 128 + kc * 8) * 1024;            \
      _Pragma("unroll")                                                     \
      for (int j_ = 0; j_ < 8; ++j_)                                        \
          P[j_] = *(const int4*)(gp_ + (size_t)j_ * 1024);                  \
      SS = *(const float4*)(sqp + (size_t)(S) * 1024); }

#define G2_DEQW(S, P, SS)                                                   \
    { unsigned char* bp_ = &blds[(S) & 1][0];                               \
      _Pragma("unroll")                                                     \
      for (int c_ = 0; c_ < 4; ++c_) {                                      \
          float s_ = QC(SS, c_);                                            \
          float o_ = -8.f * s_;                                             \
          uint4 h_;                                                         \
          h_.x = pack2bf((float)QC(P[0], c_) * s_ + o_, (float)QC(P[1], c_) * s_ + o_); \
          h_.y = pack2bf((float)QC(P[2], c_) * s_ + o_, (float)QC(P[3], c_) * s_ + o_); \
          h_.z = pack2bf((float)QC(P[4], c_) * s_ + o_, (float)QC(P[5], c_) * s_ + o_); \
          h_.w = pack2bf((float)QC(P[6], c_) * s_ + o_, (float)QC(P[7], c_) * s_ + o_); \
          *(uint4*)(bp_ + wro[c_]) = h_;                                    \
      } }

#define G2_STAGE(S, PD, SD, PI, SI)                                         \
    { const char* at_ = abase + (size_t)(S) * 4096;                         \
      bf16x8 a_[4][4];                                                      \
      _Pragma("unroll")                                                     \
      for (int ss_ = 0; ss_ < 4; ++ss_)                                     \
          _Pragma("unroll")                                                 \
          for (int mi_ = 0; mi_ < 4; ++mi_)                                 \
              a_[ss_][mi_] = *(const bf16x8*)(at_ + ss_ * 1024 + aoff[mi_]); \
      __builtin_amdgcn_sched_barrier(0);                                    \
      if ((S) + 2 < 11) { G2_ISSUE((S) + 2, PI, SI) }                       \
      __builtin_amdgcn_sched_barrier(0);                                    \
      const unsigned char* bp_ = &blds[(S) & 1][0];                         \
      __builtin_amdgcn_s_setprio(1);                                        \
      _Pragma("unroll")                                                     \
      for (int nf_ = 0; nf_ < 2; ++nf_) {                                   \
          _Pragma("unroll")                                                 \
          for (int ss_ = 0; ss_ < 4; ++ss_) {                               \
              bf16x8 b_ = *(const bf16x8*)(bp_ + rdo[nf_] + ss_ * 1024);    \
              _Pragma("unroll")                                             \
              for (int mi_ = 0; mi_ < 4; ++mi_)                             \
                  acc[mi_][nf_] = __builtin_amdgcn_mfma_f32_16x16x32_bf16(a_[ss_][mi_], b_, acc[mi_][nf_], 0, 0, 0); \
          } }                                                               \
      __builtin_amdgcn_s_setprio(0);                                        \
      if ((S) + 1 < 11) { G2_DEQW((S) + 1, PD, SD) }                        \
      asm volatile("s_waitcnt lgkmcnt(0)" ::: "memory");                    \
      __builtin_amdgcn_s_barrier();                                         \
      asm volatile("" ::: "memory"); }

    const char* abase = (const char*)actf + seg * 45056 + lq * 256 + l15 * 16;

    for (int tb = 0; tb < npad; tb += 128) {
        int aoff[4];
#pragma unroll
        for (int mi = 0; mi < 4; ++mi) {
            int R = tb + mh * 64 + mi * 16;
            R = min(R, npad - 16);
            aoff[mi] = ((pb + R) >> 4) * 180224;
        }
        f32x4 acc[4][2];
#pragma unroll
        for (int mi = 0; mi < 4; ++mi)
#pragma unroll
            for (int nf = 0; nf < 2; ++nf)
                acc[mi][nf] = (f32x4){0.f, 0.f, 0.f, 0.f};

        G2_ISSUE(0, Pa, Sa)
        G2_ISSUE(1, Pb, Sb)
        G2_DEQW(0, Pa, Sa)
        asm volatile("s_waitcnt lgkmcnt(0)" ::: "memory");
        __builtin_amdgcn_s_barrier();
        asm volatile("" ::: "memory");

#pragma unroll 1
        for (int s2 = 0; s2 < 5; ++s2) {
            G2_STAGE(2 * s2,     Pb, Sb, Pa, Sa)
            G2_STAGE(2 * s2 + 1, Pa, Sa, Pb, Sb)
        }
        G2_STAGE(10, Pb, Sb, Pa, Sa)

#pragma unroll
        for (int mi = 0; mi < 4; ++mi) {
#pragma unroll
            for (int r = 0; r < 4; ++r) {
                int m = tb + mh * 64 + mi * 16 + lq * 4 + r;
                if (m < n) {
                    float* yr = y + ((size_t)seg * NPAD_MAX + pb + m) * 1024;
                    int dc = dt * 128 + colg * 32 + l15;
                    yr[dc]      = acc[mi][0][r];
                    yr[dc + 16] = acc[mi][1][r];
                }
            }
        }
    }
#undef G2_ISSUE
#undef G2_DEQW
#undef G2_STAGE
}

// --------------------------------------------------------------- combine ---
__global__ void combine_kernel(const float* __restrict__ y,
                               const int* __restrict__ eslot,
                               const float* __restrict__ tokw,
                               const int* __restrict__ basep,
                               float* __restrict__ out)
{
    int idx = blockIdx.x * blockDim.x + threadIdx.x;
    int t  = idx >> 8;
    int dc = idx & 255;
    int es0 = eslot[t * 2 + 0], es1 = eslot[t * 2 + 1];
    float w0 = tokw[t * 2 + 0], w1 = tokw[t * 2 + 1];
    int p0 = basep[es0 >> 10] + (es0 & 1023);
    int p1 = basep[es1 >> 10] + (es1 & 1023);
    const float4* y4 = (const float4*)y;
    float4 o = (float4){0.f, 0.f, 0.f, 0.f};
#pragma unroll
    for (int seg = 0; seg < 4; ++seg) {
        float4 a = y4[((size_t)seg * NPAD_MAX + p0) * 256 + dc];
        float4 b = y4[((size_t)seg * NPAD_MAX + p1) * 256 + dc];
        o.x += w0 * a.x + w1 * b.x;
        o.y += w0 * a.y + w1 * b.y;
        o.z += w0 * a.z + w1 * b.z;
        o.w += w0 * a.w + w1 * b.w;
    }
    ((float4*)out)[idx] = o;
}

// ---------------------------------------------------------------- launch ---
extern "C" void kernel_launch(void* const* d_in, const int* in_sizes, int n_in,
                              void* d_out, int out_size, void* d_ws, size_t ws_size,
                              hipStream_t stream)
{
    const float* x    = (const float*)d_in[0];
    const float* gate = (const float*)d_in[1];
    const int*   w1q  = (const int*)d_in[2];
    const int*   w2q  = (const int*)d_in[3];
    const float* w1s  = (const float*)d_in[4];
    const float* w2s  = (const float*)d_in[5];
    float* out = (float*)d_out;
    int*   wsi = (int*)d_ws;
    float* wsf = (float*)d_ws;

    int*   cnt   = wsi + WS_CNT;
    int*   basep = wsi + WS_BASEP;
    int*   eslot = wsi + WS_ESLOT;
    float* tokw  = wsf + WS_TOKW;
    int*   etok  = wsi + WS_ETOK;
    unsigned short* actf = (unsigned short*)((char*)d_ws + WS_ACTF_B);
    unsigned short* xgf  = (unsigned short*)((char*)d_ws + WS_XGF_B);
    float*          y    = (float*)((char*)d_ws + WS_Y_B);

    routing_kernel<<<1, 1024, 0, stream>>>(gate, cnt, basep, eslot, tokw, etok);
    gather_cast_kernel<<<E_ * 64, 256, 0, stream>>>(x, cnt, basep, etok, xgf);
    gemm1_kernel<<<E_ * 44, 512, 0, stream>>>(xgf, w1q, w1s, cnt, basep, actf);
    gemm2_kernel<<<E_ * 8 * 4, 512, 0, stream>>>(actf, w2q, w2s, cnt, basep, y);
    combine_kernel<<<(T_ * D_ / 4) / 256, 256, 0, stream>>>(y, eslot, tokw, basep, out);
}

// Round 6
// 817.624 us; speedup vs baseline: 1.3356x; 1.0596x over previous
//
#include <hip/hip_runtime.h>
#include <cstdint>
#include <cstddef>

#define E_ 8
#define T_ 1024
#define D_ 1024
#define I_ 5632
#define TWO_I_ 11264
#define NPAD_MAX 2176                 /* 2048 + 8*16 */
#define NGRP_MAX 136

// ws layout (bytes): int tables in [0,64K), then act_f, then xg_f, y overlays xg_f
#define WS_ACTF_B 65536
#define WS_XGF_B  (65536 + 24510464)              /* act_f = 136*180224      */
#define WS_Y_B    WS_XGF_B                        /* y overlays dead xg_f    */
// int-table offsets (units of 4 B)
#define WS_CNT   0
#define WS_BASEP 8
#define WS_ESLOT 16
#define WS_TOKW  2064
#define WS_ETOK  4112

typedef __attribute__((ext_vector_type(8))) __bf16 bf16x8;
typedef __attribute__((ext_vector_type(4))) float  f32x4;

__device__ __forceinline__ unsigned f2bf(float f) {
    unsigned u = __float_as_uint(f);
    u += 0x7fffu + ((u >> 16) & 1u);
    return u >> 16;
}
__device__ __forceinline__ unsigned pack2bf(float f0, float f1) {
    unsigned a0 = __float_as_uint(f0); a0 += 0x7fffu + ((a0 >> 16) & 1u);
    unsigned a1 = __float_as_uint(f1); a1 += 0x7fffu + ((a1 >> 16) & 1u);
    return (a0 >> 16) | (a1 & 0xffff0000u);
}
#define QC(P, c) ((c) == 0 ? (P).x : (c) == 1 ? (P).y : (c) == 2 ? (P).z : (P).w)

// ---------------------------------------------------------------- routing ---
__global__ void routing_kernel(const float* __restrict__ gate,
                               int* cnt, int* basep, int* eslot,
                               float* tokw, int* etok)
{
    int t = threadIdx.x;
    if (t < E_) cnt[t] = 0;
    __syncthreads();
    float g[E_];
#pragma unroll
    for (int e = 0; e < E_; ++e) g[e] = gate[t * E_ + e];
    int i0 = 0; float p0 = g[0];
#pragma unroll
    for (int e = 1; e < E_; ++e) if (g[e] > p0) { p0 = g[e]; i0 = e; }
    int i1 = -1; float p1 = -1e30f;
#pragma unroll
    for (int e = 0; e < E_; ++e) if (e != i0 && g[e] > p1) { p1 = g[e]; i1 = e; }
    float w0 = 1.0f / (1.0f + expf(p1 - p0));
    float w1 = 1.0f - w0;
    int s0 = atomicAdd(&cnt[i0], 1);
    int s1 = atomicAdd(&cnt[i1], 1);
    etok[i0 * T_ + s0] = t;
    etok[i1 * T_ + s1] = t;
    eslot[t * 2 + 0] = i0 * T_ + s0;  tokw[t * 2 + 0] = w0;
    eslot[t * 2 + 1] = i1 * T_ + s1;  tokw[t * 2 + 1] = w1;
    __syncthreads();
    if (t == 0) {
        int r = 0;
#pragma unroll
        for (int e = 0; e < E_; ++e) { basep[e] = r; r += (cnt[e] + 15) & ~15; }
    }
}

// ------------------- gather x rows, cast bf16, fragment-major swizzle -------
__global__ void gather_cast_kernel(const float* __restrict__ x,
                                   const int* __restrict__ cnt,
                                   const int* __restrict__ basep,
                                   const int* __restrict__ etok,
                                   unsigned short* __restrict__ xgf)
{
    int e = blockIdx.x >> 6, g = blockIdx.x & 63;
    int n = cnt[e];
    if (g * 16 >= n) return;
    int tid = threadIdx.x;
    int row = g * 16 + (tid & 15);
    row = min(row, n - 1);
    int tok = etok[e * T_ + row];
    const float* xr = x + (size_t)tok * D_;
    unsigned short* dst = xgf + ((size_t)(basep[e] >> 4) + g) * 16384;
#pragma unroll
    for (int it = 0; it < 8; ++it) {
        int c = it * 16 + (tid >> 4);          // k-chunk 0..127
        float4 v0 = *(const float4*)(xr + c * 8);
        float4 v1 = *(const float4*)(xr + c * 8 + 4);
        uint4 h;
        h.x = pack2bf(v0.x, v0.y); h.y = pack2bf(v0.z, v0.w);
        h.z = pack2bf(v1.x, v1.y); h.w = pack2bf(v1.z, v1.w);
        *(uint4*)(dst + c * 128 + (tid & 15) * 8) = h;
    }
}

// ------------------------------------------------- gemm1: xg@w1 + silu -----
// grid = 3520 (E x 88 cg x 5 rb), 256 thr (4 waves). Tile 64 rows x 128
// B-cols (64 gate + 64 up). BK=64, 16 stages. rb-siblings (same e,cg) are
// pinned to the SAME XCD in consecutive dispatch slots -> the w1q column
// band (0.7 MB) is HBM-fetched once, siblings hit L2. Staging: thread owns
// 4 cols x 8 k (8x dwordx4, 512-B runs), in-reg dequant, 4x ds_write_b128
// into XOR cell slots (write AND read phases conflict-free). Single-P
// prefetch: issue stage S+1 at start of S, dequant at end (stage >> HBM
// latency). A-loads precede B-issue so counted vmcnt keeps B in flight.
__global__ __launch_bounds__(256, 3) void gemm1_kernel(
    const unsigned short* __restrict__ xgf, const int* __restrict__ w1q,
    const float* __restrict__ w1s, const int* __restrict__ cnt,
    const int* __restrict__ basep, unsigned short* __restrict__ actf)
{
    __shared__ unsigned char blds[2][16384];
    int b = blockIdx.x;
    int xcd = b & 7, sl = b >> 3;
    int q5 = sl / 5, rb = sl - q5 * 5;
    int cb = q5 * 8 + xcd;
    int e = cb / 88, cg = cb - e * 88;

    int n = cnt[e];
    if (n <= 0) return;
    int npad = (n + 15) & ~15;
    if (rb * 64 >= npad) return;
    int pb = basep[e];

    int tid = threadIdx.x, lane = tid & 63, w = tid >> 6;
    int l15 = lane & 15, lq = lane >> 4;

    // staging role: thread (colq 0..31, kc 0..7) owns 4 cols x 8 k
    int colq = tid & 31, kc = tid >> 5;
    int bcol = colq * 4;
    int jb = (bcol < 64) ? (cg * 64 + bcol) : (I_ + cg * 64 + (bcol - 64));
    const int*   gq  = w1q + ((size_t)e * 1024 + kc * 8) * TWO_I_ + jb;
    const float* sqp = w1s + (size_t)e * 8 * TWO_I_ + jb;
    int fcw  = colq >> 2;                      // 0..7
    int pzw  = (fcw & 3) | ((fcw >> 2) << 4);
    int lanp = (kc & 3) * 16 + (colq & 3) * 4;
    unsigned wbase = (unsigned)fcw * 2048 + (unsigned)(kc >> 2) * 1024;
    unsigned wro[4];
#pragma unroll
    for (int c = 0; c < 4; ++c)
        wro[c] = wbase + (unsigned)(((lanp + c) ^ pzw) << 4);

    // compute-side: wave w -> gate frag fc=w, up frag fc=w+4
    unsigned rg0 = (unsigned)w * 2048 + (unsigned)((lane ^ w) << 4);
    int pzu = w | 16;
    unsigned ru0 = (unsigned)(w + 4) * 2048 + (unsigned)((lane ^ pzu) << 4);

    const char* abase = (const char*)xgf + lane * 16;

    int4 P[8]; float4 SS;

#define G1_ISSUE(S)                                                         \
    { _Pragma("unroll")                                                     \
      for (int j_ = 0; j_ < 8; ++j_)                                        \
          P[j_] = *(const int4*)(gq + (size_t)((S) * 64 + j_) * TWO_I_);    \
      SS = *(const float4*)(sqp + (size_t)((S) >> 1) * TWO_I_); }

#define G1_DEQW(S)                                                          \
    { unsigned char* bp_ = &blds[(S) & 1][0];                               \
      _Pragma("unroll")                                                     \
      for (int c_ = 0; c_ < 4; ++c_) {                                      \
          float s_ = QC(SS, c_); float o_ = -8.f * s_;                      \
          uint4 h_;                                                         \
          h_.x = pack2bf((float)QC(P[0], c_) * s_ + o_, (float)QC(P[1], c_) * s_ + o_); \
          h_.y = pack2bf((float)QC(P[2], c_) * s_ + o_, (float)QC(P[3], c_) * s_ + o_); \
          h_.z = pack2bf((float)QC(P[4], c_) * s_ + o_, (float)QC(P[5], c_) * s_ + o_); \
          h_.w = pack2bf((float)QC(P[6], c_) * s_ + o_, (float)QC(P[7], c_) * s_ + o_); \
          *(uint4*)(bp_ + wro[c_]) = h_;                                    \
      } }

    for (int tb = rb * 64; tb < npad; tb += 320) {
        int aoff[4];
#pragma unroll
        for (int mi = 0; mi < 4; ++mi) {
            int R = tb + mi * 16;
            R = min(R, npad - 16);
            aoff[mi] = ((pb + R) >> 4) * 32768;
        }
        f32x4 accg[4], accu[4];
#pragma unroll
        for (int mi = 0; mi < 4; ++mi) {
            accg[mi] = (f32x4){0.f, 0.f, 0.f, 0.f};
            accu[mi] = (f32x4){0.f, 0.f, 0.f, 0.f};
        }

        G1_ISSUE(0)
        G1_DEQW(0)
        asm volatile("s_waitcnt lgkmcnt(0)" ::: "memory");
        __builtin_amdgcn_s_barrier();
        asm volatile("" ::: "memory");

#pragma unroll 2
        for (int st = 0; st < 16; ++st) {
            const char* at = abase + (size_t)st * 2048;
            bf16x8 a0[4], a1[4];
#pragma unroll
            for (int mi = 0; mi < 4; ++mi)
                a0[mi] = *(const bf16x8*)(at + aoff[mi]);
#pragma unroll
            for (int mi = 0; mi < 4; ++mi)
                a1[mi] = *(const bf16x8*)(at + 1024 + aoff[mi]);
            if (st + 1 < 16) { G1_ISSUE(st + 1) }
            const unsigned char* bp = &blds[st & 1][0];
            bf16x8 bg0 = *(const bf16x8*)(bp + rg0);
            bf16x8 bu0 = *(const bf16x8*)(bp + ru0);
            bf16x8 bg1 = *(const bf16x8*)(bp + rg0 + 1024);
            bf16x8 bu1 = *(const bf16x8*)(bp + ru0 + 1024);
            __builtin_amdgcn_s_setprio(1);
#pragma unroll
            for (int mi = 0; mi < 4; ++mi) {
                accg[mi] = __builtin_amdgcn_mfma_f32_16x16x32_bf16(a0[mi], bg0, accg[mi], 0, 0, 0);
                accu[mi] = __builtin_amdgcn_mfma_f32_16x16x32_bf16(a0[mi], bu0, accu[mi], 0, 0, 0);
            }
#pragma unroll
            for (int mi = 0; mi < 4; ++mi) {
                accg[mi] = __builtin_amdgcn_mfma_f32_16x16x32_bf16(a1[mi], bg1, accg[mi], 0, 0, 0);
                accu[mi] = __builtin_amdgcn_mfma_f32_16x16x32_bf16(a1[mi], bu1, accu[mi], 0, 0, 0);
            }
            __builtin_amdgcn_s_setprio(0);
            if (st + 1 < 16) { G1_DEQW(st + 1) }
            asm volatile("s_waitcnt lgkmcnt(0)" ::: "memory");
            __builtin_amdgcn_s_barrier();
            asm volatile("" ::: "memory");
        }

        // epilogue: silu(gate)*up -> act_f fragment-major
#pragma unroll
        for (int mi = 0; mi < 4; ++mi) {
#pragma unroll
            for (int r = 0; r < 4; ++r) {
                int m = tb + mi * 16 + lq * 4 + r;
                if (m < npad) {
                    float gv = accg[mi][r], uv = accu[mi][r];
                    float av = gv / (1.f + __expf(-gv)) * uv;
                    int prow = pb + m;
                    int icol = cg * 64 + w * 16 + l15;
                    size_t o = (size_t)(prow >> 4) * 90112 + (icol >> 3) * 128
                             + (prow & 15) * 8 + (icol & 7);
                    actf[o] = (unsigned short)f2bf(av);
                }
            }
        }
    }
#undef G1_ISSUE
#undef G1_DEQW
}

// ---------------------------------------------------- gemm2: act@w2 --------
// grid = 1280 (E x 8 dt x 4 seg x 5 rb, XCD-pinned rb-siblings), 256 thr.
// Tile 64 rows x 128 cols, K/seg = 1408 (22 stages of BK=64). Same staging
// structure as gemm1; B runs are 512 B contiguous (w2q row = 4 KB).
__global__ __launch_bounds__(256, 3) void gemm2_kernel(
    const unsigned short* __restrict__ actf, const int* __restrict__ w2q,
    const float* __restrict__ w2s, const int* __restrict__ cnt,
    const int* __restrict__ basep, float* __restrict__ y)
{
    __shared__ unsigned char blds[2][16384];
    int b = blockIdx.x;
    int xcd = b & 7, sl = b >> 3;
    int q5 = sl / 5, rb = sl - q5 * 5;
    int cb = q5 * 8 + xcd;                     // 0..255
    int e = cb >> 5, r5 = cb & 31;
    int dt = r5 >> 2, seg = r5 & 3;

    int n = cnt[e];
    if (n <= 0) return;
    int npad = (n + 15) & ~15;
    if (rb * 64 >= npad) return;
    int pb = basep[e];

    int tid = threadIdx.x, lane = tid & 63, w = tid >> 6;
    int l15 = lane & 15, lq = lane >> 4;

    int colq = tid & 31, kc = tid >> 5;
    int colb = dt * 128 + colq * 4;
    const int*   gq  = w2q + ((size_t)e * 5632 + seg * 1408 + kc * 8) * 1024 + colb;
    const float* sqp = w2s + ((size_t)e * 44 + seg * 11) * 1024 + colb;
    int fcw  = colq >> 2;
    int pzw  = (fcw & 3) | ((fcw >> 2) << 4);
    int lanp = (kc & 3) * 16 + (colq & 3) * 4;
    unsigned wbase = (unsigned)fcw * 2048 + (unsigned)(kc >> 2) * 1024;
    unsigned wro[4];
#pragma unroll
    for (int c = 0; c < 4; ++c)
        wro[c] = wbase + (unsigned)(((lanp + c) ^ pzw) << 4);

    unsigned rg0 = (unsigned)w * 2048 + (unsigned)((lane ^ w) << 4);
    int pzu = w | 16;
    unsigned ru0 = (unsigned)(w + 4) * 2048 + (unsigned)((lane ^ pzu) << 4);

    const char* abase = (const char*)actf + seg * 45056 + lane * 16;

    int4 P[8]; float4 SS;

#define G2_ISSUE(S)                                                         \
    { _Pragma("unroll")                                                     \
      for (int j_ = 0; j_ < 8; ++j_)                                        \
          P[j_] = *(const int4*)(gq + (size_t)((S) * 64 + j_) * 1024);      \
      SS = *(const float4*)(sqp + (size_t)((S) >> 1) * 1024); }

#define G2_DEQW(S)                                                          \
    { unsigned char* bp_ = &blds[(S) & 1][0];                               \
      _Pragma("unroll")                                                     \
      for (int c_ = 0; c_ < 4; ++c_) {                                      \
          float s_ = QC(SS, c_); float o_ = -8.f * s_;                      \
          uint4 h_;                                                         \
          h_.x = pack2bf((float)QC(P[0], c_) * s_ + o_, (float)QC(P[1], c_) * s_ + o_); \
          h_.y = pack2bf((float)QC(P[2], c_) * s_ + o_, (float)QC(P[3], c_) * s_ + o_); \
          h_.z = pack2bf((float)QC(P[4], c_) * s_ + o_, (float)QC(P[5], c_) * s_ + o_); \
          h_.w = pack2bf((float)QC(P[6], c_) * s_ + o_, (float)QC(P[7], c_) * s_ + o_); \
          *(uint4*)(bp_ + wro[c_]) = h_;                                    \
      } }

    for (int tb = rb * 64; tb < npad; tb += 320) {
        int aoff[4];
#pragma unroll
        for (int mi = 0; mi < 4; ++mi) {
            int R = tb + mi * 16;
            R = min(R, npad - 16);
            aoff[mi] = ((pb + R) >> 4) * 180224;
        }
        f32x4 acc0[4], acc1[4];
#pragma unroll
        for (int mi = 0; mi < 4; ++mi) {
            acc0[mi] = (f32x4){0.f, 0.f, 0.f, 0.f};
            acc1[mi] = (f32x4){0.f, 0.f, 0.f, 0.f};
        }

        G2_ISSUE(0)
        G2_DEQW(0)
        asm volatile("s_waitcnt lgkmcnt(0)" ::: "memory");
        __builtin_amdgcn_s_barrier();
        asm volatile("" ::: "memory");

#pragma unroll 2
        for (int st = 0; st < 22; ++st) {
            const char* at = abase + (size_t)st * 2048;
            bf16x8 a0[4], a1[4];
#pragma unroll
            for (int mi = 0; mi < 4; ++mi)
                a0[mi] = *(const bf16x8*)(at + aoff[mi]);
#pragma unroll
            for (int mi = 0; mi < 4; ++mi)
                a1[mi] = *(const bf16x8*)(at + 1024 + aoff[mi]);
            if (st + 1 < 22) { G2_ISSUE(st + 1) }
            const unsigned char* bp = &blds[st & 1][0];
            bf16x8 b00 = *(const bf16x8*)(bp + rg0);
            bf16x8 b10 = *(const bf16x8*)(bp + ru0);
            bf16x8 b01 = *(const bf16x8*)(bp + rg0 + 1024);
            bf16x8 b11 = *(const bf16x8*)(bp + ru0 + 1024);
            __builtin_amdgcn_s_setprio(1);
#pragma unroll
            for (int mi = 0; mi < 4; ++mi) {
                acc0[mi] = __builtin_amdgcn_mfma_f32_16x16x32_bf16(a0[mi], b00, acc0[mi], 0, 0, 0);
                acc1[mi] = __builtin_amdgcn_mfma_f32_16x16x32_bf16(a0[mi], b10, acc1[mi], 0, 0, 0);
            }
#pragma unroll
            for (int mi = 0; mi < 4; ++mi) {
                acc0[mi] = __builtin_amdgcn_mfma_f32_16x16x32_bf16(a1[mi], b01, acc0[mi], 0, 0, 0);
                acc1[mi] = __builtin_amdgcn_mfma_f32_16x16x32_bf16(a1[mi], b11, acc1[mi], 0, 0, 0);
            }
            __builtin_amdgcn_s_setprio(0);
            if (st + 1 < 22) { G2_DEQW(st + 1) }
            asm volatile("s_waitcnt lgkmcnt(0)" ::: "memory");
            __builtin_amdgcn_s_barrier();
            asm volatile("" ::: "memory");
        }

#pragma unroll
        for (int mi = 0; mi < 4; ++mi) {
#pragma unroll
            for (int r = 0; r < 4; ++r) {
                int m = tb + mi * 16 + lq * 4 + r;
                if (m < n) {
                    float* yr = y + ((size_t)seg * NPAD_MAX + pb + m) * 1024;
                    int dc = dt * 128 + w * 16 + l15;
                    yr[dc]      = acc0[mi][r];
                    yr[dc + 64] = acc1[mi][r];
                }
            }
        }
    }
#undef G2_ISSUE
#undef G2_DEQW
}

// --------------------------------------------------------------- combine ---
__global__ void combine_kernel(const float* __restrict__ y,
                               const int* __restrict__ eslot,
                               const float* __restrict__ tokw,
                               const int* __restrict__ basep,
                               float* __restrict__ out)
{
    int idx = blockIdx.x * blockDim.x + threadIdx.x;
    int t  = idx >> 8;
    int dc = idx & 255;
    int es0 = eslot[t * 2 + 0], es1 = eslot[t * 2 + 1];
    float w0 = tokw[t * 2 + 0], w1 = tokw[t * 2 + 1];
    int p0 = basep[es0 >> 10] + (es0 & 1023);
    int p1 = basep[es1 >> 10] + (es1 & 1023);
    const float4* y4 = (const float4*)y;
    float4 o = (float4){0.f, 0.f, 0.f, 0.f};
#pragma unroll
    for (int seg = 0; seg < 4; ++seg) {
        float4 a = y4[((size_t)seg * NPAD_MAX + p0) * 256 + dc];
        float4 b = y4[((size_t)seg * NPAD_MAX + p1) * 256 + dc];
        o.x += w0 * a.x + w1 * b.x;
        o.y += w0 * a.y + w1 * b.y;
        o.z += w0 * a.z + w1 * b.z;
        o.w += w0 * a.w + w1 * b.w;
    }
    ((float4*)out)[idx] = o;
}

// ---------------------------------------------------------------- launch ---
extern "C" void kernel_launch(void* const* d_in, const int* in_sizes, int n_in,
                              void* d_out, int out_size, void* d_ws, size_t ws_size,
                              hipStream_t stream)
{
    const float* x    = (const float*)d_in[0];
    const float* gate = (const float*)d_in[1];
    const int*   w1q  = (const int*)d_in[2];
    const int*   w2q  = (const int*)d_in[3];
    const float* w1s  = (const float*)d_in[4];
    const float* w2s  = (const float*)d_in[5];
    float* out = (float*)d_out;
    int*   wsi = (int*)d_ws;
    float* wsf = (float*)d_ws;

    int*   cnt   = wsi + WS_CNT;
    int*   basep = wsi + WS_BASEP;
    int*   eslot = wsi + WS_ESLOT;
    float* tokw  = wsf + WS_TOKW;
    int*   etok  = wsi + WS_ETOK;
    unsigned short* actf = (unsigned short*)((char*)d_ws + WS_ACTF_B);
    unsigned short* xgf  = (unsigned short*)((char*)d_ws + WS_XGF_B);
    float*          y    = (float*)((char*)d_ws + WS_Y_B);

    routing_kernel<<<1, 1024, 0, stream>>>(gate, cnt, basep, eslot, tokw, etok);
    gather_cast_kernel<<<E_ * 64, 256, 0, stream>>>(x, cnt, basep, etok, xgf);
    gemm1_kernel<<<E_ * 88 * 5, 256, 0, stream>>>(xgf, w1q, w1s, cnt, basep, actf);
    gemm2_kernel<<<E_ * 8 * 4 * 5, 256, 0, stream>>>(actf, w2q, w2s, cnt, basep, y);
    combine_kernel<<<(T_ * D_ / 4) / 256, 256, 0, stream>>>(y, eslot, tokw, basep, out);
}